// Round 5
// baseline (276.716 us; speedup 1.0000x reference)
//
#include <hip/hip_runtime.h>
#include <stdint.h>

#define NLAYERS 6
#define DD      128   // patch dim
#define CONDD   128
#define HID     256
#define DIN     192
#define TM      64    // tokens per block
#define NTHR    512   // 8 waves

typedef __attribute__((ext_vector_type(4))) float f32x4;
typedef __attribute__((ext_vector_type(2))) float f32x2;
typedef __attribute__((ext_vector_type(8))) short short8;

// packed-weight geometry (16x16x32 bf16 MFMA B-fragments)
#define G1_KS 2
#define G2_KS 8
#define G3_KS 8
#define G1_FR (G1_KS*16)             // 32 frags
#define G2_FR (G2_KS*16)             // 128
#define G3_FR (G3_KS*8)              // 64
#define FR_L  (G1_FR+G2_FR+G3_FR)    // 224 frags / layer
#define EL_L  (FR_L*512)             // bf16 elems / layer
#define G2_OFF (G1_FR*512)
#define G3_OFF ((G1_FR+G2_FR)*512)

__device__ __forceinline__ short f2bf(float f) {   // fp32 -> bf16 (RNE)
  uint32_t u = __builtin_bit_cast(uint32_t, f);
  u += 0x7fffu + ((u >> 16) & 1u);
  return (short)(u >> 16);
}
__device__ __forceinline__ uint32_t pack2bf(float a, float b) { // lo=a, hi=b
  uint32_t ua = __builtin_bit_cast(uint32_t, a);
  ua += 0x7fffu + ((ua >> 16) & 1u);
  uint32_t ub = __builtin_bit_cast(uint32_t, b);
  ub += 0x7fffu + ((ub >> 16) & 1u);
  return (ua >> 16) | (ub & 0xffff0000u);
}
// LDS swizzle for bf16 activation tiles
__device__ __forceinline__ int SW(int row) { return ((row & 7) << 4) ^ ((row & 8) << 2); }
// κ⁻¹: phys position p in a κ-packed 256-wide h-buffer -> logical feature index
__device__ __forceinline__ int kinv(int p) {
  return (p & ~63) | (p & 32) | ((p & 1) << 4) | ((p >> 1) & 15);
}

// Pack weights into bf16 MFMA B-fragment layout.
// W2/W3 K-rows are permuted by κ⁻¹ to match the κ-packed h1/h2 LDS layout.
__global__ void prep_weights(const float* __restrict__ W1,
                             const float* __restrict__ W2,
                             const float* __restrict__ W3,
                             short* __restrict__ wp)
{
  int t = blockIdx.x * 256 + threadIdx.x;      // 6*224*64 = 86016 threads exactly
  int lay  = t / (FR_L * 64);
  int rem  = t - lay * (FR_L * 64);
  int frag = rem >> 6;
  int lane = rem & 63;
  const float* src;
  int N, f2, dstbase, nfr, perm;
  if (frag < G1_FR) {
    f2 = frag;                  src = W1 + (size_t)lay * DIN * HID; N = HID; dstbase = 0;      nfr = 16; perm = 0;
  } else if (frag < G1_FR + G2_FR) {
    f2 = frag - G1_FR;          src = W2 + (size_t)lay * HID * HID; N = HID; dstbase = G2_OFF; nfr = 16; perm = 1;
  } else {
    f2 = frag - (G1_FR + G2_FR);src = W3 + (size_t)lay * HID * DD;  N = DD;  dstbase = G3_OFF; nfr = 8;  perm = 1;
  }
  int ks = f2 / nfr, nf = f2 - ks * nfr;
  int n  = nf * 16 + (lane & 15);
  int k0 = ks * 32 + (lane >> 4) * 8;
  short8 v;
#pragma unroll
  for (int j = 0; j < 8; ++j) {
    int k = perm ? kinv(k0 + j) : (k0 + j);
    v[j] = f2bf(src[(size_t)k * N + n]);
  }
  *(short8*)(wp + (size_t)lay * EL_L + dstbase + ((size_t)f2 * 64 + lane) * 8) = v;
}

// c1[lay][batch][h] = cond[batch] @ W1[lay][64:192][h] + b1[lay][h]  (fp32, logical h)
__global__ void prep_c1(const float* __restrict__ cond, const float* __restrict__ W1,
                        const float* __restrict__ b1, float* __restrict__ c1)
{
  int lay = blockIdx.x >> 9;
  int b   = blockIdx.x & 511;
  int h   = threadIdx.x;
  const float* wb = W1 + (size_t)lay * DIN * HID + 64 * HID + h;
  const float* cb = cond + b * CONDD;
  float acc = b1[lay * HID + h];
#pragma unroll 4
  for (int c = 0; c < CONDD; ++c) acc = fmaf(cb[c], wb[(size_t)c * HID], acc);
  c1[((size_t)lay * 512 + b) * HID + h] = acc;
}

__global__ __launch_bounds__(NTHR, 4)
void flow_kernel(const float* __restrict__ x,
                 const float* __restrict__ c1g, const float* __restrict__ b2g,
                 const float* __restrict__ b3g, const short* __restrict__ wp,
                 float* __restrict__ outz, float* __restrict__ outld)
{
  __shared__ alignas(16) short bufA[TM * 64];    // x1 bf16 (logical cols).   8KB
  __shared__ alignas(16) short bufB[TM * HID];   // h1 bf16 κ-packed / stf.  32KB
  __shared__ alignas(16) short bufC[TM * HID];   // h2 bf16 κ-packed.        32KB
  __shared__ float red[8];

  const int tid  = threadIdx.x;
  const int wave = tid >> 6;
  const int lane = tid & 63;
  const int l15  = lane & 15;
  const int l4   = lane >> 4;
  const int mq   = wave >> 1;                // row-quarter (0..3): rows 16*mq..16*mq+15
  const int nh   = wave & 1;                 // col-half (0..1): cols 128*nh..
  const int t0   = blockIdx.x * TM;
  const int batch = t0 >> 7;                 // one batch per block (2 blocks/batch)
  float* stf = (float*)bufB;                 // [64][128] fp32 st, κ3-packed (overlay)

  // z in registers: thread owns dims (d, 64+d) of tokens m = wave+8j.
  float zlo[8], zhi[8];
  int d = lane;
  {
    const float* xb = x + (size_t)t0 * DD + wave * DD + lane;
#pragma unroll
    for (int j = 0; j < 8; ++j) {
      zlo[j] = xb[j * 8 * DD];
      zhi[j] = xb[j * 8 * DD + 64];
    }
#pragma unroll
    for (int j = 0; j < 8; ++j) {            // stage x1 (bf16) for layer 0
      int m = wave + 8 * j;
      *(short*)((char*)bufA + (((m * 64 + d) * 2) ^ SW(m))) = f2bf(zlo[j]);
    }
  }
  float ldsum = 0.f;
  const f32x4 vzero = {0.f, 0.f, 0.f, 0.f};
  __syncthreads();

#pragma unroll 1
  for (int lay = 0; lay < NLAYERS; ++lay) {
    const short* wl = wp + (size_t)lay * EL_L;

    // ---- GEMM1: [64x64] @ W1a[64x256] + c1, relu -> bufB (κ-packed) ----
    // wave = 16 rows (mq) x 128 cols (nh): 8 n-frags, 1 A-read per ks.
    {
      f32x4 acc[8];
#pragma unroll
      for (int nf = 0; nf < 8; ++nf) acc[nf] = vzero;
#pragma unroll 1
      for (int ks = 0; ks < G1_KS; ++ks) {
        int row = 16 * mq + l15;
        short8 a = *(const short8*)((const char*)bufA +
                     (((row * 64 + ks * 32 + l4 * 8) * 2) ^ SW(row)));
        short8 bb[8];
#pragma unroll
        for (int nf = 0; nf < 8; ++nf)
          bb[nf] = *(const short8*)(wl + (((ks * 16 + 8 * nh + nf) * 64 + lane) * 8));
#pragma unroll
        for (int nf = 0; nf < 8; ++nf)
          acc[nf] = __builtin_amdgcn_mfma_f32_16x16x32_bf16(a, bb[nf], acc[nf], 0, 0, 0);
      }
      const float* c1row = c1g + ((size_t)lay * 512 + batch) * HID;
#pragma unroll
      for (int q = 0; q < 4; ++q) {
        int c0 = 128 * nh + 32 * q + l15;
        float bias0 = c1row[c0], bias1 = c1row[c0 + 16];
#pragma unroll
        for (int r = 0; r < 4; ++r) {
          int row = 16 * mq + 4 * l4 + r;
          float v0 = fmaxf(acc[2 * q][r] + bias0, 0.f);
          float v1 = fmaxf(acc[2 * q + 1][r] + bias1, 0.f);
          *(uint32_t*)((char*)bufB +
            (((row * HID + 128 * nh + 32 * q + 2 * l15) * 2) ^ SW(row))) = pack2bf(v0, v1);
        }
      }
    }
    __syncthreads();                         // h1 ready

    // ---- GEMM2: bufB @ W2[256x256] + b2, relu -> bufC (κ-packed) ----
    {
      const short* wg = wl + G2_OFF;
      f32x4 acc[8];
#pragma unroll
      for (int nf = 0; nf < 8; ++nf) acc[nf] = vzero;
#pragma unroll 1
      for (int ks = 0; ks < G2_KS; ++ks) {
        int row = 16 * mq + l15;
        short8 a = *(const short8*)((const char*)bufB +
                     (((row * HID + ks * 32 + l4 * 8) * 2) ^ SW(row)));
        short8 bb[8];
#pragma unroll
        for (int nf = 0; nf < 8; ++nf)
          bb[nf] = *(const short8*)(wg + (((ks * 16 + 8 * nh + nf) * 64 + lane) * 8));
#pragma unroll
        for (int nf = 0; nf < 8; ++nf)
          acc[nf] = __builtin_amdgcn_mfma_f32_16x16x32_bf16(a, bb[nf], acc[nf], 0, 0, 0);
      }
#pragma unroll
      for (int q = 0; q < 4; ++q) {
        int c0 = 128 * nh + 32 * q + l15;
        float bias0 = b2g[lay * HID + c0], bias1 = b2g[lay * HID + c0 + 16];
#pragma unroll
        for (int r = 0; r < 4; ++r) {
          int row = 16 * mq + 4 * l4 + r;
          float v0 = fmaxf(acc[2 * q][r] + bias0, 0.f);
          float v1 = fmaxf(acc[2 * q + 1][r] + bias1, 0.f);
          *(uint32_t*)((char*)bufC +
            (((row * HID + 128 * nh + 32 * q + 2 * l15) * 2) ^ SW(row))) = pack2bf(v0, v1);
        }
      }
    }
    __syncthreads();                         // h2 ready; bufB(h1) reads done

    // ---- GEMM3: bufC @ W3[256x128] + b3 -> stf (fp32, κ3-packed, overlays bufB) ----
    // wave = 16 rows (mq) x 64 cols (nh): 4 n-frags, 1 A-read per ks.
    {
      f32x4 acc3[4];
#pragma unroll
      for (int nf = 0; nf < 4; ++nf) acc3[nf] = vzero;
#pragma unroll 1
      for (int ks = 0; ks < G3_KS; ++ks) {
        int row = 16 * mq + l15;
        short8 a = *(const short8*)((const char*)bufC +
                     (((row * HID + ks * 32 + l4 * 8) * 2) ^ SW(row)));
        short8 bb[4];
#pragma unroll
        for (int nf = 0; nf < 4; ++nf)
          bb[nf] = *(const short8*)(wl + G3_OFF + (((ks * 8 + 4 * nh + nf) * 64 + lane) * 8));
#pragma unroll
        for (int nf = 0; nf < 4; ++nf)
          acc3[nf] = __builtin_amdgcn_mfma_f32_16x16x32_bf16(a, bb[nf], acc3[nf], 0, 0, 0);
      }
#pragma unroll
      for (int h = 0; h < 2; ++h) {
        int c0 = 64 * nh + 32 * h + l15;
        float bias0 = b3g[lay * DD + c0], bias1 = b3g[lay * DD + c0 + 16];
#pragma unroll
        for (int r = 0; r < 4; ++r) {
          int row = 16 * mq + 4 * l4 + r;
          f32x2 val = {acc3[2 * h][r] + bias0, acc3[2 * h + 1][r] + bias1};
          *(f32x2*)((char*)stf +
            (((row * DD + 64 * nh + 32 * h + 2 * l15) * 4) ^ (((row >> 2) & 1) << 6))) = val;
        }
      }
    }
    __syncthreads();                         // st ready

    // ---- epilogue: coupling + flip (register relabeling) ----
    int ps = (d & 32) | ((d & 15) << 1) | ((d >> 4) & 1);   // κ3(d); κ3(64+d)=64+ps
#pragma unroll
    for (int j = 0; j < 8; ++j) {
      int m = wave + 8 * j;
      int rsw = ((m >> 2) & 1) << 6;
      float sr = *(const float*)((const char*)stf + (((m * DD + ps) * 4) ^ rsw));
      float tt = *(const float*)((const char*)stf + (((m * DD + 64 + ps) * 4) ^ rsw));
      sr = fminf(fmaxf(sr, -8.f), 8.f);
      float e2 = __expf(2.f * sr);
      float s  = 0.5f * (e2 - 1.f) / (e2 + 1.f);   // 0.5*tanh(sr)
      ldsum += s;
      float y2 = fmaf(zhi[j], __expf(s), tt);
      zhi[j] = zlo[j];
      zlo[j] = y2;
    }
    d = 63 - d;                               // the flip
    if (lay < NLAYERS - 1) {
#pragma unroll
      for (int j = 0; j < 8; ++j) {          // stage next layer's x1 (bf16, logical)
        int m = wave + 8 * j;
        *(short*)((char*)bufA + (((m * 64 + d) * 2) ^ SW(m))) = f2bf(zlo[j]);
      }
    }
    __syncthreads();                         // stf reads done; bufA ready
  }

  { // store z (d == lane again after 6 flips)
    float* ob = outz + (size_t)t0 * DD + wave * DD;
#pragma unroll
    for (int j = 0; j < 8; ++j) {
      ob[j * 8 * DD + d]      = zlo[j];
      ob[j * 8 * DD + 64 + d] = zhi[j];
    }
  }
  // logdet: wave shuffle-reduce -> block -> one atomic (2 blocks/batch, commutative)
#pragma unroll
  for (int off = 32; off > 0; off >>= 1) ldsum += __shfl_down(ldsum, off);
  if (lane == 0) red[wave] = ldsum;
  __syncthreads();
  if (tid == 0) {
    float s = 0.f;
#pragma unroll
    for (int w = 0; w < 8; ++w) s += red[w];
    atomicAdd(&outld[batch], s);
  }
}

extern "C" void kernel_launch(void* const* d_in, const int* in_sizes, int n_in,
                              void* d_out, int out_size, void* d_ws, size_t ws_size,
                              hipStream_t stream)
{
  (void)in_sizes; (void)n_in; (void)out_size; (void)ws_size;
  const float* x   = (const float*)d_in[0];
  const float* cnd = (const float*)d_in[1];
  const float* W1  = (const float*)d_in[2];
  const float* b1  = (const float*)d_in[3];
  const float* W2  = (const float*)d_in[4];
  const float* b2  = (const float*)d_in[5];
  const float* W3  = (const float*)d_in[6];
  const float* b3  = (const float*)d_in[7];
  float* outz  = (float*)d_out;
  float* outld = outz + (size_t)512 * 128 * 128;
  short* wp = (short*)d_ws;                            // 1.38 MB packed bf16 weights
  float* c1 = (float*)((char*)d_ws + (2u << 20));      // 3.1 MB fp32 cond-bias

  hipMemsetAsync(outld, 0, 512 * sizeof(float), stream);
  prep_weights<<<336, 256, 0, stream>>>(W1, W2, W3, wp);
  prep_c1<<<6 * 512, 256, 0, stream>>>(cnd, W1, b1, c1);
  flow_kernel<<<1024, NTHR, 0, stream>>>(x, c1, b2, b3, wp, outz, outld);
}

// Round 6
// 172.716 us; speedup vs baseline: 1.6021x; 1.6021x over previous
//
#include <hip/hip_runtime.h>
#include <stdint.h>

#define NLAYERS 6
#define DD      128   // patch dim
#define CONDD   128
#define HID     256
#define DIN     192
#define TM      64    // tokens per block
#define NTHR    512   // 8 waves

typedef __attribute__((ext_vector_type(4))) float f32x4;
typedef __attribute__((ext_vector_type(8))) short short8;

// packed-weight geometry (16x16x32 bf16 MFMA B-fragments)
#define G1_KS 2
#define G2_KS 8
#define G3_KS 8
#define G1_FR (G1_KS*16)             // 32 frags
#define G2_FR (G2_KS*16)             // 128
#define G3_FR (G3_KS*8)              // 64
#define FR_L  (G1_FR+G2_FR+G3_FR)    // 224 frags / layer
#define EL_L  (FR_L*512)             // bf16 elems / layer
#define G2_OFF (G1_FR*512)
#define G3_OFF ((G1_FR+G2_FR)*512)

__device__ __forceinline__ short f2bf(float f) {   // fp32 -> bf16 (RNE)
  uint32_t u = __builtin_bit_cast(uint32_t, f);
  u += 0x7fffu + ((u >> 16) & 1u);
  return (short)(u >> 16);
}
__device__ __forceinline__ uint32_t pack2bf(float a, float b) { // lo=a, hi=b
  uint32_t ua = __builtin_bit_cast(uint32_t, a);
  ua += 0x7fffu + ((ua >> 16) & 1u);
  uint32_t ub = __builtin_bit_cast(uint32_t, b);
  ub += 0x7fffu + ((ub >> 16) & 1u);
  return (ua >> 16) | (ub & 0xffff0000u);
}
// LDS swizzle for bf16 activation tiles
__device__ __forceinline__ int SW(int row) { return ((row & 7) << 4) ^ ((row & 8) << 2); }
// κ⁻¹: phys position p in a κ-packed 256-wide h-buffer -> logical feature index
__device__ __forceinline__ int kinv(int p) {
  return (p & ~63) | (p & 32) | ((p & 1) << 4) | ((p >> 1) & 15);
}

// Pack weights into bf16 MFMA B-fragment layout.
// W2/W3 K-rows permuted by κ⁻¹ (they consume κ-packed h1/h2).
// W3 output cols permuted by σ: phys col (32g+16h+lv) -> logical c+64h where
// c = lv<8 ? 8g+lv : 48-8g+lv  (flip-symmetric per wave: 63-c <-> lane^15).
__global__ void prep_weights(const float* __restrict__ W1,
                             const float* __restrict__ W2,
                             const float* __restrict__ W3,
                             short* __restrict__ wp)
{
  int t = blockIdx.x * 256 + threadIdx.x;      // 6*224*64 = 86016 threads exactly
  int lay  = t / (FR_L * 64);
  int rem  = t - lay * (FR_L * 64);
  int frag = rem >> 6;
  int lane = rem & 63;
  const float* src;
  int N, f2, dstbase, nfr, perm;
  if (frag < G1_FR) {
    f2 = frag;                  src = W1 + (size_t)lay * DIN * HID; N = HID; dstbase = 0;      nfr = 16; perm = 0;
  } else if (frag < G1_FR + G2_FR) {
    f2 = frag - G1_FR;          src = W2 + (size_t)lay * HID * HID; N = HID; dstbase = G2_OFF; nfr = 16; perm = 1;
  } else {
    f2 = frag - (G1_FR + G2_FR);src = W3 + (size_t)lay * HID * DD;  N = DD;  dstbase = G3_OFF; nfr = 8;  perm = 2;
  }
  int ks = f2 / nfr, nf = f2 - ks * nfr;
  int lv = lane & 15;
  int n;
  if (perm == 2) {               // σ: pair s/t for the same logical col
    int g = nf >> 1, h = nf & 1;
    int c = (lv < 8) ? 8 * g + lv : 48 - 8 * g + lv;
    n = c + 64 * h;
  } else {
    n = nf * 16 + lv;
  }
  int k0 = ks * 32 + (lane >> 4) * 8;
  short8 v;
#pragma unroll
  for (int j = 0; j < 8; ++j) {
    int k = perm ? kinv(k0 + j) : (k0 + j);
    v[j] = f2bf(src[(size_t)k * N + n]);
  }
  *(short8*)(wp + (size_t)lay * EL_L + dstbase + ((size_t)f2 * 64 + lane) * 8) = v;
}

// c1[lay][batch][h] = cond[batch] @ W1[lay][64:192][h] + b1[lay][h]  (fp32, logical h)
__global__ void prep_c1(const float* __restrict__ cond, const float* __restrict__ W1,
                        const float* __restrict__ b1, float* __restrict__ c1)
{
  int lay = blockIdx.x >> 9;
  int b   = blockIdx.x & 511;
  int h   = threadIdx.x;
  const float* wb = W1 + (size_t)lay * DIN * HID + 64 * HID + h;
  const float* cb = cond + b * CONDD;
  float acc = b1[lay * HID + h];
#pragma unroll 4
  for (int c = 0; c < CONDD; ++c) acc = fmaf(cb[c], wb[(size_t)c * HID], acc);
  c1[((size_t)lay * 512 + b) * HID + h] = acc;
}

__global__ __launch_bounds__(NTHR, 4)
void flow_kernel(const float* __restrict__ x,
                 const float* __restrict__ c1g, const float* __restrict__ b2g,
                 const float* __restrict__ b3g, const short* __restrict__ wp,
                 float* __restrict__ outz, float* __restrict__ outld)
{
  __shared__ alignas(16) short bufA[TM * 64];    // x1 bf16 (logical cols).   8KB
  __shared__ alignas(16) short bufB[TM * HID];   // h1 bf16 κ-packed.        32KB
  __shared__ alignas(16) short bufC[TM * HID];   // h2 bf16 κ-packed.        32KB
  __shared__ float red[8];

  const int tid  = threadIdx.x;
  const int wave = tid >> 6;
  const int lane = tid & 63;
  const int l15  = lane & 15;
  const int l4   = lane >> 4;
  const int mh   = wave >> 2;                // row-half (0..1): rows 32*mh..
  const int nq   = wave & 3;                 // col-quarter (0..3)
  const int t0   = blockIdx.x * TM;
  const int batch = t0 >> 7;                 // one batch per block (2 blocks/batch)

  // z ownership matches GEMM3's output distribution: this thread owns the
  // dim-pair (cT, 64+cT) of 8 tokens m = 32mh + 16m2 + 4l4 + r.
  const int cT = (l15 < 8) ? 8 * nq + l15 : 48 - 8 * nq + l15;
  float zlo[8], zhi[8];                      // zlo = z[m,cT] (x1), zhi = z[m,64+cT] (x2)
  {
    const float* xb = x + (size_t)t0 * DD;
#pragma unroll
    for (int m2 = 0; m2 < 2; ++m2)
#pragma unroll
      for (int r = 0; r < 4; ++r) {
        int j = m2 * 4 + r;
        int row = 32 * mh + 16 * m2 + 4 * l4 + r;
        zlo[j] = xb[row * DD + cT];
        zhi[j] = xb[row * DD + 64 + cT];
      }
#pragma unroll
    for (int m2 = 0; m2 < 2; ++m2)           // stage x1 (bf16) for layer 0
#pragma unroll
      for (int r = 0; r < 4; ++r) {
        int row = 32 * mh + 16 * m2 + 4 * l4 + r;
        *(short*)((char*)bufA + (((row * 64 + cT) * 2) ^ SW(row))) = f2bf(zlo[m2 * 4 + r]);
      }
  }
  float ldsum = 0.f;
  const f32x4 vzero = {0.f, 0.f, 0.f, 0.f};
  __syncthreads();

#pragma unroll 1
  for (int lay = 0; lay < NLAYERS; ++lay) {
    const short* wl = wp + (size_t)lay * EL_L;

    // ---- GEMM1: [64x64] @ W1a[64x256] + c1, relu -> bufB (κ-packed) ----
    {
      f32x4 acc[2][4];
#pragma unroll
      for (int m2 = 0; m2 < 2; ++m2)
#pragma unroll
        for (int nf = 0; nf < 4; ++nf) acc[m2][nf] = vzero;
#pragma unroll
      for (int ks = 0; ks < G1_KS; ++ks) {
        short8 bb[4];
#pragma unroll
        for (int nf = 0; nf < 4; ++nf)
          bb[nf] = *(const short8*)(wl + (((ks * 16 + 4 * nq + nf) * 64 + lane) * 8));
#pragma unroll
        for (int m2 = 0; m2 < 2; ++m2) {
          int row = 32 * mh + 16 * m2 + l15;
          short8 a = *(const short8*)((const char*)bufA +
                       (((row * 64 + ks * 32 + l4 * 8) * 2) ^ SW(row)));
#pragma unroll
          for (int nf = 0; nf < 4; ++nf)
            acc[m2][nf] = __builtin_amdgcn_mfma_f32_16x16x32_bf16(a, bb[nf], acc[m2][nf], 0, 0, 0);
        }
      }
      const float* c1row = c1g + ((size_t)lay * 512 + batch) * HID;
#pragma unroll
      for (int h = 0; h < 2; ++h) {
        int c0 = 64 * nq + 32 * h + l15;
        float bias0 = c1row[c0], bias1 = c1row[c0 + 16];
#pragma unroll
        for (int m2 = 0; m2 < 2; ++m2)
#pragma unroll
          for (int r = 0; r < 4; ++r) {
            int row = 32 * mh + 16 * m2 + 4 * l4 + r;
            float v0 = fmaxf(acc[m2][2 * h][r] + bias0, 0.f);
            float v1 = fmaxf(acc[m2][2 * h + 1][r] + bias1, 0.f);
            *(uint32_t*)((char*)bufB +
              (((row * HID + 64 * nq + 32 * h + 2 * l15) * 2) ^ SW(row))) = pack2bf(v0, v1);
          }
      }
    }
    __syncthreads();                         // B1: h1 ready

    // ---- GEMM2: bufB @ W2[256x256] + b2, relu -> bufC (κ-packed) ----
    {
      const short* wg = wl + G2_OFF;
      f32x4 acc[2][4];
#pragma unroll
      for (int m2 = 0; m2 < 2; ++m2)
#pragma unroll
        for (int nf = 0; nf < 4; ++nf) acc[m2][nf] = vzero;
#pragma unroll 2
      for (int ks = 0; ks < G2_KS; ++ks) {
        short8 bb[4];
#pragma unroll
        for (int nf = 0; nf < 4; ++nf)
          bb[nf] = *(const short8*)(wg + (((ks * 16 + 4 * nq + nf) * 64 + lane) * 8));
#pragma unroll
        for (int m2 = 0; m2 < 2; ++m2) {
          int row = 32 * mh + 16 * m2 + l15;
          short8 a = *(const short8*)((const char*)bufB +
                       (((row * HID + ks * 32 + l4 * 8) * 2) ^ SW(row)));
#pragma unroll
          for (int nf = 0; nf < 4; ++nf)
            acc[m2][nf] = __builtin_amdgcn_mfma_f32_16x16x32_bf16(a, bb[nf], acc[m2][nf], 0, 0, 0);
        }
      }
#pragma unroll
      for (int h = 0; h < 2; ++h) {
        int c0 = 64 * nq + 32 * h + l15;
        float bias0 = b2g[lay * HID + c0], bias1 = b2g[lay * HID + c0 + 16];
#pragma unroll
        for (int m2 = 0; m2 < 2; ++m2)
#pragma unroll
          for (int r = 0; r < 4; ++r) {
            int row = 32 * mh + 16 * m2 + 4 * l4 + r;
            float v0 = fmaxf(acc[m2][2 * h][r] + bias0, 0.f);
            float v1 = fmaxf(acc[m2][2 * h + 1][r] + bias1, 0.f);
            *(uint32_t*)((char*)bufC +
              (((row * HID + 64 * nq + 32 * h + 2 * l15) * 2) ^ SW(row))) = pack2bf(v0, v1);
          }
      }
    }
    __syncthreads();                         // B2: h2 ready; bufB(h1) reads done

    // ---- GEMM3 + coupling, fully in registers (σ-paired s,t) ----
    {
      f32x4 acc3[2][2];
#pragma unroll
      for (int m2 = 0; m2 < 2; ++m2) { acc3[m2][0] = vzero; acc3[m2][1] = vzero; }
#pragma unroll 2
      for (int ks = 0; ks < G3_KS; ++ks) {
        short8 bb[2];
#pragma unroll
        for (int nf = 0; nf < 2; ++nf)
          bb[nf] = *(const short8*)(wl + G3_OFF + (((ks * 8 + 2 * nq + nf) * 64 + lane) * 8));
#pragma unroll
        for (int m2 = 0; m2 < 2; ++m2) {
          int row = 32 * mh + 16 * m2 + l15;
          short8 a = *(const short8*)((const char*)bufC +
                       (((row * HID + ks * 32 + l4 * 8) * 2) ^ SW(row)));
          acc3[m2][0] = __builtin_amdgcn_mfma_f32_16x16x32_bf16(a, bb[0], acc3[m2][0], 0, 0, 0);
          acc3[m2][1] = __builtin_amdgcn_mfma_f32_16x16x32_bf16(a, bb[1], acc3[m2][1], 0, 0, 0);
        }
      }
      float bias_s = b3g[lay * DD + cT];
      float bias_t = b3g[lay * DD + 64 + cT];
      // coupling: y2 = x2*exp(s)+t; flip: new (zlo,zhi)[cT] = (y2,x1)[63-cT],
      // and 63-cT lives at lane^15 (σ is flip-symmetric per wave).
#pragma unroll
      for (int m2 = 0; m2 < 2; ++m2)
#pragma unroll
        for (int r = 0; r < 4; ++r) {
          int j = m2 * 4 + r;
          float sr = acc3[m2][0][r] + bias_s;
          sr = fminf(fmaxf(sr, -8.f), 8.f);
          float tt = acc3[m2][1][r] + bias_t;
          float e2 = __expf(2.f * sr);
          float s  = 0.5f * (e2 - 1.f) / (e2 + 1.f);   // 0.5*tanh(sr)
          ldsum += s;
          float y2 = fmaf(zhi[j], __expf(s), tt);
          float py = __shfl_xor(y2, 15);       // partner's y2  -> new x1 half
          float pl = __shfl_xor(zlo[j], 15);   // partner's x1  -> new x2 half
          zlo[j] = py;
          zhi[j] = pl;
        }
      if (lay < NLAYERS - 1) {
#pragma unroll
        for (int m2 = 0; m2 < 2; ++m2)         // stage next layer's x1 (bf16)
#pragma unroll
          for (int r = 0; r < 4; ++r) {
            int row = 32 * mh + 16 * m2 + 4 * l4 + r;
            *(short*)((char*)bufA + (((row * 64 + cT) * 2) ^ SW(row))) = f2bf(zlo[m2 * 4 + r]);
          }
        __syncthreads();                       // B3: bufA ready (skip on last layer)
      }
    }
  }

  { // store z
    float* ob = outz + (size_t)t0 * DD;
#pragma unroll
    for (int m2 = 0; m2 < 2; ++m2)
#pragma unroll
      for (int r = 0; r < 4; ++r) {
        int j = m2 * 4 + r;
        int row = 32 * mh + 16 * m2 + 4 * l4 + r;
        ob[row * DD + cT]      = zlo[j];
        ob[row * DD + 64 + cT] = zhi[j];
      }
  }
  // logdet: wave shuffle-reduce -> block -> one atomic (2 blocks/batch, commutative)
#pragma unroll
  for (int off = 32; off > 0; off >>= 1) ldsum += __shfl_down(ldsum, off);
  if (lane == 0) red[wave] = ldsum;
  __syncthreads();
  if (tid == 0) {
    float s = 0.f;
#pragma unroll
    for (int w = 0; w < 8; ++w) s += red[w];
    atomicAdd(&outld[batch], s);
  }
}

extern "C" void kernel_launch(void* const* d_in, const int* in_sizes, int n_in,
                              void* d_out, int out_size, void* d_ws, size_t ws_size,
                              hipStream_t stream)
{
  (void)in_sizes; (void)n_in; (void)out_size; (void)ws_size;
  const float* x   = (const float*)d_in[0];
  const float* cnd = (const float*)d_in[1];
  const float* W1  = (const float*)d_in[2];
  const float* b1  = (const float*)d_in[3];
  const float* W2  = (const float*)d_in[4];
  const float* b2  = (const float*)d_in[5];
  const float* W3  = (const float*)d_in[6];
  const float* b3  = (const float*)d_in[7];
  float* outz  = (float*)d_out;
  float* outld = outz + (size_t)512 * 128 * 128;
  short* wp = (short*)d_ws;                            // 1.38 MB packed bf16 weights
  float* c1 = (float*)((char*)d_ws + (2u << 20));      // 3.1 MB fp32 cond-bias

  hipMemsetAsync(outld, 0, 512 * sizeof(float), stream);
  prep_weights<<<336, 256, 0, stream>>>(W1, W2, W3, wp);
  prep_c1<<<6 * 512, 256, 0, stream>>>(cnd, W1, b1, c1);
  flow_kernel<<<1024, NTHR, 0, stream>>>(x, c1, b2, b3, wp, outz, outld);
}

// Round 7
// 164.185 us; speedup vs baseline: 1.6854x; 1.0520x over previous
//
#include <hip/hip_runtime.h>
#include <stdint.h>

#define NLAYERS 6
#define DD      128   // patch dim
#define CONDD   128
#define HID     256
#define DIN     192
#define TM      64    // tokens per block
#define NTHR    512   // 8 waves

typedef __attribute__((ext_vector_type(4))) float f32x4;
typedef __attribute__((ext_vector_type(8))) short short8;

// packed-weight geometry (16x16x32 bf16 MFMA B-fragments)
#define G1_KS 2
#define G2_KS 8
#define G3_KS 8
#define G1_FR (G1_KS*16)             // 32 frags
#define G2_FR (G2_KS*16)             // 128
#define G3_FR (G3_KS*8)              // 64
#define FR_L  (G1_FR+G2_FR+G3_FR)    // 224 frags / layer
#define EL_L  (FR_L*512)             // bf16 elems / layer
#define G2_OFF (G1_FR*512)
#define G3_OFF ((G1_FR+G2_FR)*512)

__device__ __forceinline__ short f2bf(float f) {   // fp32 -> bf16 (RNE), scalar
  uint32_t u = __builtin_bit_cast(uint32_t, f);
  u += 0x7fffu + ((u >> 16) & 1u);
  return (short)(u >> 16);
}
// HW packed convert: dst = {bf16(hi),bf16(lo)} in one instruction (saves ~5 VALU + temps)
__device__ __forceinline__ uint32_t cvtpk(float lo, float hi) {
  uint32_t r;
  asm("v_cvt_pk_bf16_f32 %0, %1, %2" : "=v"(r) : "v"(lo), "v"(hi));
  return r;
}
// LDS swizzle for bf16 activation tiles
__device__ __forceinline__ int SW(int row) { return ((row & 7) << 4) ^ ((row & 8) << 2); }
// κ⁻¹: phys position p in a κ-packed 256-wide h-buffer -> logical feature index
__device__ __forceinline__ int kinv(int p) {
  return (p & ~63) | (p & 32) | ((p & 1) << 4) | ((p >> 1) & 15);
}

// Pack weights into bf16 MFMA B-fragment layout.
// W2/W3 K-rows permuted by κ⁻¹ (they consume κ-packed h1/h2).
// W3 output cols permuted by σ: phys col (32g+16h+lv) -> logical c+64h where
// c = lv<8 ? 8g+lv : 48-8g+lv  (flip-symmetric per wave: 63-c <-> lane^15).
__global__ void prep_weights(const float* __restrict__ W1,
                             const float* __restrict__ W2,
                             const float* __restrict__ W3,
                             short* __restrict__ wp)
{
  int t = blockIdx.x * 256 + threadIdx.x;      // 6*224*64 = 86016 threads exactly
  int lay  = t / (FR_L * 64);
  int rem  = t - lay * (FR_L * 64);
  int frag = rem >> 6;
  int lane = rem & 63;
  const float* src;
  int N, f2, dstbase, nfr, perm;
  if (frag < G1_FR) {
    f2 = frag;                  src = W1 + (size_t)lay * DIN * HID; N = HID; dstbase = 0;      nfr = 16; perm = 0;
  } else if (frag < G1_FR + G2_FR) {
    f2 = frag - G1_FR;          src = W2 + (size_t)lay * HID * HID; N = HID; dstbase = G2_OFF; nfr = 16; perm = 1;
  } else {
    f2 = frag - (G1_FR + G2_FR);src = W3 + (size_t)lay * HID * DD;  N = DD;  dstbase = G3_OFF; nfr = 8;  perm = 2;
  }
  int ks = f2 / nfr, nf = f2 - ks * nfr;
  int lv = lane & 15;
  int n;
  if (perm == 2) {               // σ: pair s/t for the same logical col
    int g = nf >> 1, h = nf & 1;
    int c = (lv < 8) ? 8 * g + lv : 48 - 8 * g + lv;
    n = c + 64 * h;
  } else {
    n = nf * 16 + lv;
  }
  int k0 = ks * 32 + (lane >> 4) * 8;
  short8 v;
#pragma unroll
  for (int j = 0; j < 8; ++j) {
    int k = perm ? kinv(k0 + j) : (k0 + j);
    v[j] = f2bf(src[(size_t)k * N + n]);
  }
  *(short8*)(wp + (size_t)lay * EL_L + dstbase + ((size_t)f2 * 64 + lane) * 8) = v;
}

// c1[lay][batch][h] = cond[batch] @ W1[lay][64:192][h] + b1[lay][h]  (fp32, logical h)
__global__ void prep_c1(const float* __restrict__ cond, const float* __restrict__ W1,
                        const float* __restrict__ b1, float* __restrict__ c1)
{
  int lay = blockIdx.x >> 9;
  int b   = blockIdx.x & 511;
  int h   = threadIdx.x;
  const float* wb = W1 + (size_t)lay * DIN * HID + 64 * HID + h;
  const float* cb = cond + b * CONDD;
  float acc = b1[lay * HID + h];
#pragma unroll 4
  for (int c = 0; c < CONDD; ++c) acc = fmaf(cb[c], wb[(size_t)c * HID], acc);
  c1[((size_t)lay * 512 + b) * HID + h] = acc;
}

__global__ __launch_bounds__(NTHR, 4)
void flow_kernel(const float* __restrict__ x,
                 const float* __restrict__ c1g, const float* __restrict__ b2g,
                 const float* __restrict__ b3g, const short* __restrict__ wp,
                 float* __restrict__ outz, float* __restrict__ outld)
{
  __shared__ alignas(16) short bufA[TM * 64];    // x1 bf16 (logical cols).   8KB
  __shared__ alignas(16) short bufB[TM * HID];   // h1 bf16 κ-packed.        32KB
  __shared__ alignas(16) short bufC[TM * HID];   // h2 bf16 κ-packed.        32KB
  __shared__ float red[8];

  const int tid  = threadIdx.x;
  const int wave = tid >> 6;
  const int lane = tid & 63;
  const int l15  = lane & 15;
  const int l4   = lane >> 4;
  const int mh   = wave >> 2;                // row-half (0..1): rows 32*mh..
  const int nq   = wave & 3;                 // col-quarter (0..3)
  const int t0   = blockIdx.x * TM;
  const int batch = t0 >> 7;                 // one batch per block (2 blocks/batch)

  // z ownership matches GEMM3's output distribution: this thread owns the
  // dim-pair (cT, 64+cT) of 8 tokens m = 32mh + 16m2 + 4l4 + r.
  const int cT = (l15 < 8) ? 8 * nq + l15 : 48 - 8 * nq + l15;
  float zlo[8], zhi[8];                      // zlo = z[m,cT] (x1), zhi = z[m,64+cT] (x2)
  {
    const float* xb = x + (size_t)t0 * DD;
#pragma unroll
    for (int m2 = 0; m2 < 2; ++m2)
#pragma unroll
      for (int r = 0; r < 4; ++r) {
        int j = m2 * 4 + r;
        int row = 32 * mh + 16 * m2 + 4 * l4 + r;
        zlo[j] = xb[row * DD + cT];
        zhi[j] = xb[row * DD + 64 + cT];
      }
#pragma unroll
    for (int m2 = 0; m2 < 2; ++m2)           // stage x1 (bf16) for layer 0
#pragma unroll
      for (int r = 0; r < 4; ++r) {
        int row = 32 * mh + 16 * m2 + 4 * l4 + r;
        *(short*)((char*)bufA + (((row * 64 + cT) * 2) ^ SW(row))) = f2bf(zlo[m2 * 4 + r]);
      }
  }
  float ldsum = 0.f;
  const f32x4 vzero = {0.f, 0.f, 0.f, 0.f};
  __syncthreads();

#pragma unroll 1
  for (int lay = 0; lay < NLAYERS; ++lay) {
    const short* wl = wp + (size_t)lay * EL_L;

    // ---- GEMM1: [64x64] @ W1a[64x256] + c1, relu -> bufB (κ-packed) ----
    {
      f32x4 acc[2][4];
#pragma unroll
      for (int m2 = 0; m2 < 2; ++m2)
#pragma unroll
        for (int nf = 0; nf < 4; ++nf) acc[m2][nf] = vzero;
#pragma unroll 1
      for (int ks = 0; ks < G1_KS; ++ks) {
        short8 bb[4];
#pragma unroll
        for (int nf = 0; nf < 4; ++nf)
          bb[nf] = *(const short8*)(wl + (((ks * 16 + 4 * nq + nf) * 64 + lane) * 8));
#pragma unroll
        for (int m2 = 0; m2 < 2; ++m2) {
          int row = 32 * mh + 16 * m2 + l15;
          short8 a = *(const short8*)((const char*)bufA +
                       (((row * 64 + ks * 32 + l4 * 8) * 2) ^ SW(row)));
#pragma unroll
          for (int nf = 0; nf < 4; ++nf)
            acc[m2][nf] = __builtin_amdgcn_mfma_f32_16x16x32_bf16(a, bb[nf], acc[m2][nf], 0, 0, 0);
        }
      }
      const float* c1row = c1g + ((size_t)lay * 512 + batch) * HID;
#pragma unroll
      for (int h = 0; h < 2; ++h) {
        int c0 = 64 * nq + 32 * h + l15;
        float bias0 = c1row[c0], bias1 = c1row[c0 + 16];
#pragma unroll
        for (int m2 = 0; m2 < 2; ++m2)
#pragma unroll
          for (int r = 0; r < 4; ++r) {
            int row = 32 * mh + 16 * m2 + 4 * l4 + r;
            float v0 = fmaxf(acc[m2][2 * h][r] + bias0, 0.f);
            float v1 = fmaxf(acc[m2][2 * h + 1][r] + bias1, 0.f);
            *(uint32_t*)((char*)bufB +
              (((row * HID + 64 * nq + 32 * h + 2 * l15) * 2) ^ SW(row))) = cvtpk(v0, v1);
          }
      }
    }
    __syncthreads();                         // B1: h1 ready

    // ---- GEMM2: bufB @ W2[256x256] + b2, relu -> bufC (κ-packed) ----
    {
      const short* wg = wl + G2_OFF;
      f32x4 acc[2][4];
#pragma unroll
      for (int m2 = 0; m2 < 2; ++m2)
#pragma unroll
        for (int nf = 0; nf < 4; ++nf) acc[m2][nf] = vzero;
#pragma unroll 2
      for (int ks = 0; ks < G2_KS; ++ks) {
        short8 bb[4];
#pragma unroll
        for (int nf = 0; nf < 4; ++nf)
          bb[nf] = *(const short8*)(wg + (((ks * 16 + 4 * nq + nf) * 64 + lane) * 8));
#pragma unroll
        for (int m2 = 0; m2 < 2; ++m2) {
          int row = 32 * mh + 16 * m2 + l15;
          short8 a = *(const short8*)((const char*)bufB +
                       (((row * HID + ks * 32 + l4 * 8) * 2) ^ SW(row)));
#pragma unroll
          for (int nf = 0; nf < 4; ++nf)
            acc[m2][nf] = __builtin_amdgcn_mfma_f32_16x16x32_bf16(a, bb[nf], acc[m2][nf], 0, 0, 0);
        }
      }
#pragma unroll
      for (int h = 0; h < 2; ++h) {
        int c0 = 64 * nq + 32 * h + l15;
        float bias0 = b2g[lay * HID + c0], bias1 = b2g[lay * HID + c0 + 16];
#pragma unroll
        for (int m2 = 0; m2 < 2; ++m2)
#pragma unroll
          for (int r = 0; r < 4; ++r) {
            int row = 32 * mh + 16 * m2 + 4 * l4 + r;
            float v0 = fmaxf(acc[m2][2 * h][r] + bias0, 0.f);
            float v1 = fmaxf(acc[m2][2 * h + 1][r] + bias1, 0.f);
            *(uint32_t*)((char*)bufC +
              (((row * HID + 64 * nq + 32 * h + 2 * l15) * 2) ^ SW(row))) = cvtpk(v0, v1);
          }
      }
    }
    __syncthreads();                         // B2: h2 ready; bufB(h1) reads done

    // ---- GEMM3 + coupling, fully in registers (σ-paired s,t) ----
    {
      f32x4 acc3[2][2];
#pragma unroll
      for (int m2 = 0; m2 < 2; ++m2) { acc3[m2][0] = vzero; acc3[m2][1] = vzero; }
#pragma unroll 2
      for (int ks = 0; ks < G3_KS; ++ks) {
        short8 bb[2];
#pragma unroll
        for (int nf = 0; nf < 2; ++nf)
          bb[nf] = *(const short8*)(wl + G3_OFF + (((ks * 8 + 2 * nq + nf) * 64 + lane) * 8));
#pragma unroll
        for (int m2 = 0; m2 < 2; ++m2) {
          int row = 32 * mh + 16 * m2 + l15;
          short8 a = *(const short8*)((const char*)bufC +
                       (((row * HID + ks * 32 + l4 * 8) * 2) ^ SW(row)));
          acc3[m2][0] = __builtin_amdgcn_mfma_f32_16x16x32_bf16(a, bb[0], acc3[m2][0], 0, 0, 0);
          acc3[m2][1] = __builtin_amdgcn_mfma_f32_16x16x32_bf16(a, bb[1], acc3[m2][1], 0, 0, 0);
        }
      }
      float bias_s = b3g[lay * DD + cT];
      float bias_t = b3g[lay * DD + 64 + cT];
      // coupling: y2 = x2*exp(s)+t; flip: new (zlo,zhi)[cT] = (y2,x1)[63-cT],
      // and 63-cT lives at lane^15 (σ is flip-symmetric per wave).
#pragma unroll
      for (int m2 = 0; m2 < 2; ++m2)
#pragma unroll
        for (int r = 0; r < 4; ++r) {
          int j = m2 * 4 + r;
          float sr = acc3[m2][0][r] + bias_s;
          sr = fminf(fmaxf(sr, -8.f), 8.f);
          float tt = acc3[m2][1][r] + bias_t;
          float e2 = __expf(2.f * sr);
          float s  = 0.5f * (e2 - 1.f) / (e2 + 1.f);   // 0.5*tanh(sr)
          ldsum += s;
          float y2 = fmaf(zhi[j], __expf(s), tt);
          float py = __shfl_xor(y2, 15);       // partner's y2  -> new x1 half
          float pl = __shfl_xor(zlo[j], 15);   // partner's x1  -> new x2 half
          zlo[j] = py;
          zhi[j] = pl;
        }
      if (lay < NLAYERS - 1) {
#pragma unroll
        for (int m2 = 0; m2 < 2; ++m2)         // stage next layer's x1 (bf16)
#pragma unroll
          for (int r = 0; r < 4; ++r) {
            int row = 32 * mh + 16 * m2 + 4 * l4 + r;
            *(short*)((char*)bufA + (((row * 64 + cT) * 2) ^ SW(row))) = f2bf(zlo[m2 * 4 + r]);
          }
        __syncthreads();                       // B3: bufA ready (skip on last layer)
      }
    }
  }

  { // store z
    float* ob = outz + (size_t)t0 * DD;
#pragma unroll
    for (int m2 = 0; m2 < 2; ++m2)
#pragma unroll
      for (int r = 0; r < 4; ++r) {
        int j = m2 * 4 + r;
        int row = 32 * mh + 16 * m2 + 4 * l4 + r;
        ob[row * DD + cT]      = zlo[j];
        ob[row * DD + 64 + cT] = zhi[j];
      }
  }
  // logdet: wave shuffle-reduce -> block -> one atomic (2 blocks/batch, commutative)
#pragma unroll
  for (int off = 32; off > 0; off >>= 1) ldsum += __shfl_down(ldsum, off);
  if (lane == 0) red[wave] = ldsum;
  __syncthreads();
  if (tid == 0) {
    float s = 0.f;
#pragma unroll
    for (int w = 0; w < 8; ++w) s += red[w];
    atomicAdd(&outld[batch], s);
  }
}

extern "C" void kernel_launch(void* const* d_in, const int* in_sizes, int n_in,
                              void* d_out, int out_size, void* d_ws, size_t ws_size,
                              hipStream_t stream)
{
  (void)in_sizes; (void)n_in; (void)out_size; (void)ws_size;
  const float* x   = (const float*)d_in[0];
  const float* cnd = (const float*)d_in[1];
  const float* W1  = (const float*)d_in[2];
  const float* b1  = (const float*)d_in[3];
  const float* W2  = (const float*)d_in[4];
  const float* b2  = (const float*)d_in[5];
  const float* W3  = (const float*)d_in[6];
  const float* b3  = (const float*)d_in[7];
  float* outz  = (float*)d_out;
  float* outld = outz + (size_t)512 * 128 * 128;
  short* wp = (short*)d_ws;                            // 1.38 MB packed bf16 weights
  float* c1 = (float*)((char*)d_ws + (2u << 20));      // 3.1 MB fp32 cond-bias

  hipMemsetAsync(outld, 0, 512 * sizeof(float), stream);
  prep_weights<<<336, 256, 0, stream>>>(W1, W2, W3, wp);
  prep_c1<<<6 * 512, 256, 0, stream>>>(cnd, W1, b1, c1);
  flow_kernel<<<1024, NTHR, 0, stream>>>(x, c1, b2, b3, wp, outz, outld);
}

// Round 8
// 161.565 us; speedup vs baseline: 1.7127x; 1.0162x over previous
//
#include <hip/hip_runtime.h>
#include <stdint.h>

#define NLAYERS 6
#define DD      128   // patch dim
#define CONDD   128
#define HID     256
#define DIN     192
#define TM      64    // tokens per block
#define NTHR    512   // 8 waves

typedef __attribute__((ext_vector_type(4))) float f32x4;
typedef __attribute__((ext_vector_type(8))) short short8;

// packed-weight geometry (16x16x32 bf16 MFMA B-fragments)
#define G1_KS 2
#define G2_KS 8
#define G3_KS 8
#define G1_FR (G1_KS*16)             // 32 frags
#define G2_FR (G2_KS*16)             // 128
#define G3_FR (G3_KS*8)              // 64
#define FR_L  (G1_FR+G2_FR+G3_FR)    // 224 frags / layer
#define EL_L  (FR_L*512)             // bf16 elems / layer
#define G2_OFF (G1_FR*512)
#define G3_OFF ((G1_FR+G2_FR)*512)

__device__ __forceinline__ short f2bf(float f) {   // fp32 -> bf16 (RNE), scalar
  uint32_t u = __builtin_bit_cast(uint32_t, f);
  u += 0x7fffu + ((u >> 16) & 1u);
  return (short)(u >> 16);
}
// HW packed convert: dst = {bf16(hi),bf16(lo)} in one instruction
__device__ __forceinline__ uint32_t cvtpk(float lo, float hi) {
  uint32_t r;
  asm("v_cvt_pk_bf16_f32 %0, %1, %2" : "=v"(r) : "v"(lo), "v"(hi));
  return r;
}
// LDS swizzle for bf16 activation tiles
__device__ __forceinline__ int SW(int row) { return ((row & 7) << 4) ^ ((row & 8) << 2); }
// κ⁻¹: phys position p in a κ-packed 256-wide h-buffer -> logical feature index
__device__ __forceinline__ int kinv(int p) {
  return (p & ~63) | (p & 32) | ((p & 1) << 4) | ((p >> 1) & 15);
}

// Pack weights into bf16 MFMA B-fragment layout.
// W2/W3 K-rows permuted by κ⁻¹ (they consume κ-packed h1/h2).
// W3 output cols: frag (2g+h), lane-lo lv -> logical col c_l + 64h where
// c_l = (lay even) ? 16g+lv : 63-(16g+lv).  The flip is a LABEL flip:
// threads keep (y2, x1) in place and the next layer's σ absorbs 63-c.
__global__ void prep_weights(const float* __restrict__ W1,
                             const float* __restrict__ W2,
                             const float* __restrict__ W3,
                             short* __restrict__ wp)
{
  int t = blockIdx.x * 256 + threadIdx.x;      // 6*224*64 = 86016 threads exactly
  int lay  = t / (FR_L * 64);
  int rem  = t - lay * (FR_L * 64);
  int frag = rem >> 6;
  int lane = rem & 63;
  const float* src;
  int N, f2, dstbase, nfr, perm;
  if (frag < G1_FR) {
    f2 = frag;                  src = W1 + (size_t)lay * DIN * HID; N = HID; dstbase = 0;      nfr = 16; perm = 0;
  } else if (frag < G1_FR + G2_FR) {
    f2 = frag - G1_FR;          src = W2 + (size_t)lay * HID * HID; N = HID; dstbase = G2_OFF; nfr = 16; perm = 1;
  } else {
    f2 = frag - (G1_FR + G2_FR);src = W3 + (size_t)lay * HID * DD;  N = DD;  dstbase = G3_OFF; nfr = 8;  perm = 2;
  }
  int ks = f2 / nfr, nf = f2 - ks * nfr;
  int lv = lane & 15;
  int n;
  if (perm == 2) {               // σ_l: pair (s,t) for the same logical col c_l
    int g = nf >> 1, h = nf & 1;
    int c = 16 * g + lv;
    if (lay & 1) c = 63 - c;
    n = c + 64 * h;
  } else {
    n = nf * 16 + lv;
  }
  int k0 = ks * 32 + (lane >> 4) * 8;
  short8 v;
#pragma unroll
  for (int j = 0; j < 8; ++j) {
    int k = perm ? kinv(k0 + j) : (k0 + j);
    v[j] = f2bf(src[(size_t)k * N + n]);
  }
  *(short8*)(wp + (size_t)lay * EL_L + dstbase + ((size_t)f2 * 64 + lane) * 8) = v;
}

// c1[lay][batch][h] = cond[batch] @ W1[lay][64:192][h] + b1[lay][h]  (fp32, logical h)
__global__ void prep_c1(const float* __restrict__ cond, const float* __restrict__ W1,
                        const float* __restrict__ b1, float* __restrict__ c1)
{
  int lay = blockIdx.x >> 9;
  int b   = blockIdx.x & 511;
  int h   = threadIdx.x;
  const float* wb = W1 + (size_t)lay * DIN * HID + 64 * HID + h;
  const float* cb = cond + b * CONDD;
  float acc = b1[lay * HID + h];
#pragma unroll 4
  for (int c = 0; c < CONDD; ++c) acc = fmaf(cb[c], wb[(size_t)c * HID], acc);
  c1[((size_t)lay * 512 + b) * HID + h] = acc;
}

__global__ __launch_bounds__(NTHR, 4)
void flow_kernel(const float* __restrict__ x,
                 const float* __restrict__ c1g, const float* __restrict__ b2g,
                 const float* __restrict__ b3g, const short* __restrict__ wp,
                 float* __restrict__ outz, float* __restrict__ outld)
{
  __shared__ alignas(16) short bufA[TM * 64];    // x1 bf16 (logical cols).   8KB
  __shared__ alignas(16) short bufB[TM * HID];   // h1 bf16 κ-packed.        32KB
  __shared__ alignas(16) short bufC[TM * HID];   // h2 bf16 κ-packed.        32KB
  __shared__ float red[8];

  const int tid  = threadIdx.x;
  const int wave = tid >> 6;
  const int lane = tid & 63;
  const int l15  = lane & 15;
  const int l4   = lane >> 4;
  const int mh   = wave >> 2;                // row-half (0..1): rows 32*mh..
  const int nq   = wave & 3;                 // col-quarter (0..3)
  const int t0   = blockIdx.x * TM;
  const int batch = t0 >> 7;                 // one batch per block (2 blocks/batch)

  // z ownership: this thread holds the dim-pair (c_l, 64+c_l) of its 8 rows,
  // where c_0 = 16*nq + l15 and c_{l+1} = 63 - c_l (label flip, no data motion).
  const int cB = 16 * nq + l15;
  float zlo[8], zhi[8];                      // zlo = z[m,c_l] (x1), zhi = z[m,64+c_l] (x2)
  {
    const float* xb = x + (size_t)t0 * DD;
#pragma unroll
    for (int m2 = 0; m2 < 2; ++m2)
#pragma unroll
      for (int r = 0; r < 4; ++r) {
        int j = m2 * 4 + r;
        int row = 32 * mh + 16 * m2 + 4 * l4 + r;
        zlo[j] = xb[row * DD + cB];
        zhi[j] = xb[row * DD + 64 + cB];
      }
#pragma unroll
    for (int m2 = 0; m2 < 2; ++m2)           // stage x1 (bf16) for layer 0
#pragma unroll
      for (int r = 0; r < 4; ++r) {
        int row = 32 * mh + 16 * m2 + 4 * l4 + r;
        *(short*)((char*)bufA + (((row * 64 + cB) * 2) ^ SW(row))) = f2bf(zlo[m2 * 4 + r]);
      }
  }
  float ldsum = 0.f;
  const f32x4 vzero = {0.f, 0.f, 0.f, 0.f};
  __syncthreads();

#pragma unroll 1
  for (int lay = 0; lay < NLAYERS; ++lay) {
    const short* wl = wp + (size_t)lay * EL_L;
    const int cl = (lay & 1) ? (63 - cB) : cB;   // this layer's owned column

    // ---- GEMM1: [64x64] @ W1a[64x256] + c1, relu -> bufB (κ-packed) ----
    {
      f32x4 acc[2][4];
#pragma unroll
      for (int m2 = 0; m2 < 2; ++m2)
#pragma unroll
        for (int nf = 0; nf < 4; ++nf) acc[m2][nf] = vzero;
#pragma unroll 1
      for (int ks = 0; ks < G1_KS; ++ks) {
        short8 bb[4];
#pragma unroll
        for (int nf = 0; nf < 4; ++nf)
          bb[nf] = *(const short8*)(wl + (((ks * 16 + 4 * nq + nf) * 64 + lane) * 8));
#pragma unroll
        for (int m2 = 0; m2 < 2; ++m2) {
          int row = 32 * mh + 16 * m2 + l15;
          short8 a = *(const short8*)((const char*)bufA +
                       (((row * 64 + ks * 32 + l4 * 8) * 2) ^ SW(row)));
#pragma unroll
          for (int nf = 0; nf < 4; ++nf)
            acc[m2][nf] = __builtin_amdgcn_mfma_f32_16x16x32_bf16(a, bb[nf], acc[m2][nf], 0, 0, 0);
        }
      }
      const float* c1row = c1g + ((size_t)lay * 512 + batch) * HID;
#pragma unroll
      for (int h = 0; h < 2; ++h) {
        int c0 = 64 * nq + 32 * h + l15;
        float bias0 = c1row[c0], bias1 = c1row[c0 + 16];
#pragma unroll
        for (int m2 = 0; m2 < 2; ++m2)
#pragma unroll
          for (int r = 0; r < 4; ++r) {
            int row = 32 * mh + 16 * m2 + 4 * l4 + r;
            float v0 = fmaxf(acc[m2][2 * h][r] + bias0, 0.f);
            float v1 = fmaxf(acc[m2][2 * h + 1][r] + bias1, 0.f);
            *(uint32_t*)((char*)bufB +
              (((row * HID + 64 * nq + 32 * h + 2 * l15) * 2) ^ SW(row))) = cvtpk(v0, v1);
          }
      }
    }
    __syncthreads();                         // B1: h1 ready

    // ---- GEMM2: bufB @ W2[256x256] + b2, relu -> bufC (κ-packed) ----
    {
      const short* wg = wl + G2_OFF;
      f32x4 acc[2][4];
#pragma unroll
      for (int m2 = 0; m2 < 2; ++m2)
#pragma unroll
        for (int nf = 0; nf < 4; ++nf) acc[m2][nf] = vzero;
#pragma unroll 2
      for (int ks = 0; ks < G2_KS; ++ks) {
        short8 bb[4];
#pragma unroll
        for (int nf = 0; nf < 4; ++nf)
          bb[nf] = *(const short8*)(wg + (((ks * 16 + 4 * nq + nf) * 64 + lane) * 8));
#pragma unroll
        for (int m2 = 0; m2 < 2; ++m2) {
          int row = 32 * mh + 16 * m2 + l15;
          short8 a = *(const short8*)((const char*)bufB +
                       (((row * HID + ks * 32 + l4 * 8) * 2) ^ SW(row)));
#pragma unroll
          for (int nf = 0; nf < 4; ++nf)
            acc[m2][nf] = __builtin_amdgcn_mfma_f32_16x16x32_bf16(a, bb[nf], acc[m2][nf], 0, 0, 0);
        }
      }
#pragma unroll
      for (int h = 0; h < 2; ++h) {
        int c0 = 64 * nq + 32 * h + l15;
        float bias0 = b2g[lay * HID + c0], bias1 = b2g[lay * HID + c0 + 16];
#pragma unroll
        for (int m2 = 0; m2 < 2; ++m2)
#pragma unroll
          for (int r = 0; r < 4; ++r) {
            int row = 32 * mh + 16 * m2 + 4 * l4 + r;
            float v0 = fmaxf(acc[m2][2 * h][r] + bias0, 0.f);
            float v1 = fmaxf(acc[m2][2 * h + 1][r] + bias1, 0.f);
            *(uint32_t*)((char*)bufC +
              (((row * HID + 64 * nq + 32 * h + 2 * l15) * 2) ^ SW(row))) = cvtpk(v0, v1);
          }
      }
    }
    __syncthreads();                         // B2: h2 ready; bufB(h1) reads done

    // ---- GEMM3 + coupling, fully in registers (σ_l-paired s,t; label flip) ----
    {
      f32x4 acc3[2][2];
#pragma unroll
      for (int m2 = 0; m2 < 2; ++m2) { acc3[m2][0] = vzero; acc3[m2][1] = vzero; }
#pragma unroll 2
      for (int ks = 0; ks < G3_KS; ++ks) {
        short8 bb[2];
#pragma unroll
        for (int nf = 0; nf < 2; ++nf)
          bb[nf] = *(const short8*)(wl + G3_OFF + (((ks * 8 + 2 * nq + nf) * 64 + lane) * 8));
#pragma unroll
        for (int m2 = 0; m2 < 2; ++m2) {
          int row = 32 * mh + 16 * m2 + l15;
          short8 a = *(const short8*)((const char*)bufC +
                       (((row * HID + ks * 32 + l4 * 8) * 2) ^ SW(row)));
          acc3[m2][0] = __builtin_amdgcn_mfma_f32_16x16x32_bf16(a, bb[0], acc3[m2][0], 0, 0, 0);
          acc3[m2][1] = __builtin_amdgcn_mfma_f32_16x16x32_bf16(a, bb[1], acc3[m2][1], 0, 0, 0);
        }
      }
      float bias_s = b3g[lay * DD + cl];
      float bias_t = b3g[lay * DD + 64 + cl];
      // coupling: y2 = x2*exp(s)+t.  Label flip c->63-c means the new
      // (zlo,zhi) = (y2, old x1) with NO cross-lane exchange.
#pragma unroll
      for (int m2 = 0; m2 < 2; ++m2)
#pragma unroll
        for (int r = 0; r < 4; ++r) {
          int j = m2 * 4 + r;
          float sr = acc3[m2][0][r] + bias_s;
          sr = fminf(fmaxf(sr, -8.f), 8.f);
          float tt = acc3[m2][1][r] + bias_t;
          float e2 = __expf(2.f * sr);
          float s  = 0.5f * (e2 - 1.f) / (e2 + 1.f);   // 0.5*tanh(sr)
          ldsum += s;
          float y2 = fmaf(zhi[j], __expf(s), tt);
          zhi[j] = zlo[j];                   // new x2 half = old x1
          zlo[j] = y2;                       // new x1 half = y2
        }
      if (lay < NLAYERS - 1) {
        int cn = 63 - cl;                    // next layer's owned column
#pragma unroll
        for (int m2 = 0; m2 < 2; ++m2)       // stage next layer's x1 (bf16)
#pragma unroll
          for (int r = 0; r < 4; ++r) {
            int row = 32 * mh + 16 * m2 + 4 * l4 + r;
            *(short*)((char*)bufA + (((row * 64 + cn) * 2) ^ SW(row))) = f2bf(zlo[m2 * 4 + r]);
          }
        __syncthreads();                     // B3: bufA ready (skip on last layer)
      }
    }
  }

  { // store z (c_6 = cB after 6 label flips)
    float* ob = outz + (size_t)t0 * DD;
#pragma unroll
    for (int m2 = 0; m2 < 2; ++m2)
#pragma unroll
      for (int r = 0; r < 4; ++r) {
        int j = m2 * 4 + r;
        int row = 32 * mh + 16 * m2 + 4 * l4 + r;
        ob[row * DD + cB]      = zlo[j];
        ob[row * DD + 64 + cB] = zhi[j];
      }
  }
  // logdet: wave shuffle-reduce -> block -> one atomic (2 blocks/batch, commutative)
#pragma unroll
  for (int off = 32; off > 0; off >>= 1) ldsum += __shfl_down(ldsum, off);
  if (lane == 0) red[wave] = ldsum;
  __syncthreads();
  if (tid == 0) {
    float s = 0.f;
#pragma unroll
    for (int w = 0; w < 8; ++w) s += red[w];
    atomicAdd(&outld[batch], s);
  }
}

extern "C" void kernel_launch(void* const* d_in, const int* in_sizes, int n_in,
                              void* d_out, int out_size, void* d_ws, size_t ws_size,
                              hipStream_t stream)
{
  (void)in_sizes; (void)n_in; (void)out_size; (void)ws_size;
  const float* x   = (const float*)d_in[0];
  const float* cnd = (const float*)d_in[1];
  const float* W1  = (const float*)d_in[2];
  const float* b1  = (const float*)d_in[3];
  const float* W2  = (const float*)d_in[4];
  const float* b2  = (const float*)d_in[5];
  const float* W3  = (const float*)d_in[6];
  const float* b3  = (const float*)d_in[7];
  float* outz  = (float*)d_out;
  float* outld = outz + (size_t)512 * 128 * 128;
  short* wp = (short*)d_ws;                            // 1.38 MB packed bf16 weights
  float* c1 = (float*)((char*)d_ws + (2u << 20));      // 3.1 MB fp32 cond-bias

  hipMemsetAsync(outld, 0, 512 * sizeof(float), stream);
  prep_weights<<<336, 256, 0, stream>>>(W1, W2, W3, wp);
  prep_c1<<<6 * 512, 256, 0, stream>>>(cnd, W1, b1, c1);
  flow_kernel<<<1024, NTHR, 0, stream>>>(x, c1, b2, b3, wp, outz, outld);
}

// Round 9
// 160.579 us; speedup vs baseline: 1.7232x; 1.0061x over previous
//
#include <hip/hip_runtime.h>
#include <stdint.h>

#define NLAYERS 6
#define DD      128   // patch dim
#define CONDD   128
#define HID     256
#define DIN     192
#define TM      64    // tokens per block
#define NTHR    512   // 8 waves
#define SA      72    // bufA row stride (elements): 64 + 8 pad -> 8-way bank spread
#define SB      264   // bufB/C row stride (elements): 256 + 8 pad

typedef __attribute__((ext_vector_type(4))) float f32x4;
typedef __attribute__((ext_vector_type(8))) short short8;

// packed-weight geometry (16x16x32 bf16 MFMA B-fragments)
#define G1_KS 2
#define G2_KS 8
#define G3_KS 8
#define G1_FR (G1_KS*16)             // 32 frags
#define G2_FR (G2_KS*16)             // 128
#define G3_FR (G3_KS*8)              // 64
#define FR_L  (G1_FR+G2_FR+G3_FR)    // 224 frags / layer
#define EL_L  (FR_L*512)             // bf16 elems / layer
#define G2_OFF (G1_FR*512)
#define G3_OFF ((G1_FR+G2_FR)*512)

__device__ __forceinline__ short f2bf(float f) {   // fp32 -> bf16 (RNE), scalar
  uint32_t u = __builtin_bit_cast(uint32_t, f);
  u += 0x7fffu + ((u >> 16) & 1u);
  return (short)(u >> 16);
}
// HW packed convert: dst = {bf16(hi),bf16(lo)} in one instruction
__device__ __forceinline__ uint32_t cvtpk(float lo, float hi) {
  uint32_t r;
  asm("v_cvt_pk_bf16_f32 %0, %1, %2" : "=v"(r) : "v"(lo), "v"(hi));
  return r;
}
// κ⁻¹: phys position p in a κ-packed 256-wide h-buffer -> logical feature index
__device__ __forceinline__ int kinv(int p) {
  return (p & ~63) | (p & 32) | ((p & 1) << 4) | ((p >> 1) & 15);
}

// Pack weights into bf16 MFMA B-fragment layout.
// W2/W3 K-rows permuted by κ⁻¹ (they consume κ-packed h1/h2).
// W3 output cols: frag (2g+h), lane-lo lv -> logical col c_l + 64h where
// c_l = (lay even) ? 16g+lv : 63-(16g+lv)  (label-flip coupling).
__global__ void prep_weights(const float* __restrict__ W1,
                             const float* __restrict__ W2,
                             const float* __restrict__ W3,
                             short* __restrict__ wp)
{
  int t = blockIdx.x * 256 + threadIdx.x;      // 6*224*64 = 86016 threads exactly
  int lay  = t / (FR_L * 64);
  int rem  = t - lay * (FR_L * 64);
  int frag = rem >> 6;
  int lane = rem & 63;
  const float* src;
  int N, f2, dstbase, nfr, perm;
  if (frag < G1_FR) {
    f2 = frag;                  src = W1 + (size_t)lay * DIN * HID; N = HID; dstbase = 0;      nfr = 16; perm = 0;
  } else if (frag < G1_FR + G2_FR) {
    f2 = frag - G1_FR;          src = W2 + (size_t)lay * HID * HID; N = HID; dstbase = G2_OFF; nfr = 16; perm = 1;
  } else {
    f2 = frag - (G1_FR + G2_FR);src = W3 + (size_t)lay * HID * DD;  N = DD;  dstbase = G3_OFF; nfr = 8;  perm = 2;
  }
  int ks = f2 / nfr, nf = f2 - ks * nfr;
  int lv = lane & 15;
  int n;
  if (perm == 2) {               // σ_l: pair (s,t) for the same logical col c_l
    int g = nf >> 1, h = nf & 1;
    int c = 16 * g + lv;
    if (lay & 1) c = 63 - c;
    n = c + 64 * h;
  } else {
    n = nf * 16 + lv;
  }
  int k0 = ks * 32 + (lane >> 4) * 8;
  short8 v;
#pragma unroll
  for (int j = 0; j < 8; ++j) {
    int k = perm ? kinv(k0 + j) : (k0 + j);
    v[j] = f2bf(src[(size_t)k * N + n]);
  }
  *(short8*)(wp + (size_t)lay * EL_L + dstbase + ((size_t)f2 * 64 + lane) * 8) = v;
}

// c1[lay][batch][h] = cond[batch] @ W1[lay][64:192][h] + b1[lay][h]  (fp32, logical h)
__global__ void prep_c1(const float* __restrict__ cond, const float* __restrict__ W1,
                        const float* __restrict__ b1, float* __restrict__ c1)
{
  int lay = blockIdx.x >> 9;
  int b   = blockIdx.x & 511;
  int h   = threadIdx.x;
  const float* wb = W1 + (size_t)lay * DIN * HID + 64 * HID + h;
  const float* cb = cond + b * CONDD;
  float acc = b1[lay * HID + h];
#pragma unroll 4
  for (int c = 0; c < CONDD; ++c) acc = fmaf(cb[c], wb[(size_t)c * HID], acc);
  c1[((size_t)lay * 512 + b) * HID + h] = acc;
}

__global__ __launch_bounds__(NTHR, 4)
void flow_kernel(const float* __restrict__ x,
                 const float* __restrict__ c1g, const float* __restrict__ b2g,
                 const float* __restrict__ b3g, const short* __restrict__ wp,
                 float* __restrict__ outz, float* __restrict__ outld)
{
  // Row-padded (+8 elem) LDS: every access is base + compile-time immediate;
  // bank-group of row r = (33r + l4 + 4ks)&7 -> 8-way spread, no XOR math.
  __shared__ alignas(16) short bufA[TM * SA];    // x1 bf16.                  9.0KB
  __shared__ alignas(16) short bufB[TM * SB];    // h1 bf16 κ-packed.        33.0KB
  __shared__ alignas(16) short bufC[TM * SB];    // h2 bf16 κ-packed.        33.0KB
  __shared__ float red[8];

  const int tid  = threadIdx.x;
  const int wave = tid >> 6;
  const int lane = tid & 63;
  const int l15  = lane & 15;
  const int l4   = lane >> 4;
  const int mh   = wave >> 2;                // row-half (0..1): rows 32*mh..
  const int nq   = wave & 3;                 // col-quarter (0..3)
  const int t0   = blockIdx.x * TM;
  const int batch = t0 >> 7;                 // one batch per block (2 blocks/batch)

  // z ownership: thread holds the dim-pair (c_l, 64+c_l) of its 8 rows,
  // c_0 = 16*nq + l15, c_{l+1} = 63 - c_l (label flip, no data motion).
  const int cB = 16 * nq + l15;
  const int rbase = 32 * mh + 4 * l4;        // rows rbase + 16*m2 + r
  float zlo[8], zhi[8];
  {
    const float* xb = x + (size_t)t0 * DD;
#pragma unroll
    for (int m2 = 0; m2 < 2; ++m2)
#pragma unroll
      for (int r = 0; r < 4; ++r) {
        int j = m2 * 4 + r;
        int row = rbase + 16 * m2 + r;
        zlo[j] = xb[row * DD + cB];
        zhi[j] = xb[row * DD + 64 + cB];
      }
#pragma unroll
    for (int m2 = 0; m2 < 2; ++m2)           // stage x1 (bf16) for layer 0
#pragma unroll
      for (int r = 0; r < 4; ++r) {
        int row = rbase + 16 * m2 + r;
        bufA[row * SA + cB] = f2bf(zlo[m2 * 4 + r]);
      }
  }
  float ldsum = 0.f;
  const f32x4 vzero = {0.f, 0.f, 0.f, 0.f};
  __syncthreads();

#pragma unroll 1
  for (int lay = 0; lay < NLAYERS; ++lay) {
    const short* wl = wp + (size_t)lay * EL_L;
    const int cl = (lay & 1) ? (63 - cB) : cB;   // this layer's owned column

    // ---- GEMM1: [64x64] @ W1a[64x256] + c1, relu -> bufB (κ-packed) ----
    {
      f32x4 acc[2][4];
#pragma unroll
      for (int m2 = 0; m2 < 2; ++m2)
#pragma unroll
        for (int nf = 0; nf < 4; ++nf) acc[m2][nf] = vzero;
#pragma unroll 1
      for (int ks = 0; ks < G1_KS; ++ks) {
        short8 bb[4];
#pragma unroll
        for (int nf = 0; nf < 4; ++nf)
          bb[nf] = *(const short8*)(wl + (((ks * 16 + 4 * nq + nf) * 64 + lane) * 8));
#pragma unroll
        for (int m2 = 0; m2 < 2; ++m2) {
          int row = 32 * mh + 16 * m2 + l15;
          short8 a = *(const short8*)(bufA + row * SA + ks * 32 + l4 * 8);
#pragma unroll
          for (int nf = 0; nf < 4; ++nf)
            acc[m2][nf] = __builtin_amdgcn_mfma_f32_16x16x32_bf16(a, bb[nf], acc[m2][nf], 0, 0, 0);
        }
      }
      const float* c1row = c1g + ((size_t)lay * 512 + batch) * HID;
#pragma unroll
      for (int h = 0; h < 2; ++h) {
        int c0 = 64 * nq + 32 * h + l15;
        float bias0 = c1row[c0], bias1 = c1row[c0 + 16];
#pragma unroll
        for (int m2 = 0; m2 < 2; ++m2)
#pragma unroll
          for (int r = 0; r < 4; ++r) {
            int row = rbase + 16 * m2 + r;
            float v0 = fmaxf(acc[m2][2 * h][r] + bias0, 0.f);
            float v1 = fmaxf(acc[m2][2 * h + 1][r] + bias1, 0.f);
            *(uint32_t*)(bufB + row * SB + 64 * nq + 32 * h + 2 * l15) = cvtpk(v0, v1);
          }
      }
    }
    __syncthreads();                         // B1: h1 ready

    // ---- GEMM2: bufB @ W2[256x256] + b2, relu -> bufC (κ-packed) ----
    {
      const short* wg = wl + G2_OFF;
      f32x4 acc[2][4];
#pragma unroll
      for (int m2 = 0; m2 < 2; ++m2)
#pragma unroll
        for (int nf = 0; nf < 4; ++nf) acc[m2][nf] = vzero;
#pragma unroll 2
      for (int ks = 0; ks < G2_KS; ++ks) {
        short8 bb[4];
#pragma unroll
        for (int nf = 0; nf < 4; ++nf)
          bb[nf] = *(const short8*)(wg + (((ks * 16 + 4 * nq + nf) * 64 + lane) * 8));
#pragma unroll
        for (int m2 = 0; m2 < 2; ++m2) {
          int row = 32 * mh + 16 * m2 + l15;
          short8 a = *(const short8*)(bufB + row * SB + ks * 32 + l4 * 8);
#pragma unroll
          for (int nf = 0; nf < 4; ++nf)
            acc[m2][nf] = __builtin_amdgcn_mfma_f32_16x16x32_bf16(a, bb[nf], acc[m2][nf], 0, 0, 0);
        }
      }
#pragma unroll
      for (int h = 0; h < 2; ++h) {
        int c0 = 64 * nq + 32 * h + l15;
        float bias0 = b2g[lay * HID + c0], bias1 = b2g[lay * HID + c0 + 16];
#pragma unroll
        for (int m2 = 0; m2 < 2; ++m2)
#pragma unroll
          for (int r = 0; r < 4; ++r) {
            int row = rbase + 16 * m2 + r;
            float v0 = fmaxf(acc[m2][2 * h][r] + bias0, 0.f);
            float v1 = fmaxf(acc[m2][2 * h + 1][r] + bias1, 0.f);
            *(uint32_t*)(bufC + row * SB + 64 * nq + 32 * h + 2 * l15) = cvtpk(v0, v1);
          }
      }
    }
    __syncthreads();                         // B2: h2 ready; bufB(h1) reads done

    // ---- GEMM3 + coupling, fully in registers (σ_l-paired s,t; label flip) ----
    {
      f32x4 acc3[2][2];
#pragma unroll
      for (int m2 = 0; m2 < 2; ++m2) { acc3[m2][0] = vzero; acc3[m2][1] = vzero; }
#pragma unroll 2
      for (int ks = 0; ks < G3_KS; ++ks) {
        short8 bb[2];
#pragma unroll
        for (int nf = 0; nf < 2; ++nf)
          bb[nf] = *(const short8*)(wl + G3_OFF + (((ks * 8 + 2 * nq + nf) * 64 + lane) * 8));
#pragma unroll
        for (int m2 = 0; m2 < 2; ++m2) {
          int row = 32 * mh + 16 * m2 + l15;
          short8 a = *(const short8*)(bufC + row * SB + ks * 32 + l4 * 8);
          acc3[m2][0] = __builtin_amdgcn_mfma_f32_16x16x32_bf16(a, bb[0], acc3[m2][0], 0, 0, 0);
          acc3[m2][1] = __builtin_amdgcn_mfma_f32_16x16x32_bf16(a, bb[1], acc3[m2][1], 0, 0, 0);
        }
      }
      float bias_s = b3g[lay * DD + cl];
      float bias_t = b3g[lay * DD + 64 + cl];
      // coupling: y2 = x2*exp(s)+t.  Label flip c->63-c: new (zlo,zhi) =
      // (y2, old x1) with NO cross-lane exchange.
#pragma unroll
      for (int m2 = 0; m2 < 2; ++m2)
#pragma unroll
        for (int r = 0; r < 4; ++r) {
          int j = m2 * 4 + r;
          float sr = acc3[m2][0][r] + bias_s;
          sr = fminf(fmaxf(sr, -8.f), 8.f);
          float tt = acc3[m2][1][r] + bias_t;
          float e2 = __expf(2.f * sr);
          float s  = 0.5f * (e2 - 1.f) / (e2 + 1.f);   // 0.5*tanh(sr)
          ldsum += s;
          float y2 = fmaf(zhi[j], __expf(s), tt);
          zhi[j] = zlo[j];                   // new x2 half = old x1
          zlo[j] = y2;                       // new x1 half = y2
        }
      if (lay < NLAYERS - 1) {
        int cn = 63 - cl;                    // next layer's owned column
#pragma unroll
        for (int m2 = 0; m2 < 2; ++m2)       // stage next layer's x1 (bf16)
#pragma unroll
          for (int r = 0; r < 4; ++r) {
            int row = rbase + 16 * m2 + r;
            bufA[row * SA + cn] = f2bf(zlo[m2 * 4 + r]);
          }
        __syncthreads();                     // B3: bufA ready (skip on last layer)
      }
    }
  }

  { // store z (c_6 = cB after 6 label flips)
    float* ob = outz + (size_t)t0 * DD;
#pragma unroll
    for (int m2 = 0; m2 < 2; ++m2)
#pragma unroll
      for (int r = 0; r < 4; ++r) {
        int j = m2 * 4 + r;
        int row = rbase + 16 * m2 + r;
        ob[row * DD + cB]      = zlo[j];
        ob[row * DD + 64 + cB] = zhi[j];
      }
  }
  // logdet: wave shuffle-reduce -> block -> one atomic (2 blocks/batch, commutative)
#pragma unroll
  for (int off = 32; off > 0; off >>= 1) ldsum += __shfl_down(ldsum, off);
  if (lane == 0) red[wave] = ldsum;
  __syncthreads();
  if (tid == 0) {
    float s = 0.f;
#pragma unroll
    for (int w = 0; w < 8; ++w) s += red[w];
    atomicAdd(&outld[batch], s);
  }
}

extern "C" void kernel_launch(void* const* d_in, const int* in_sizes, int n_in,
                              void* d_out, int out_size, void* d_ws, size_t ws_size,
                              hipStream_t stream)
{
  (void)in_sizes; (void)n_in; (void)out_size; (void)ws_size;
  const float* x   = (const float*)d_in[0];
  const float* cnd = (const float*)d_in[1];
  const float* W1  = (const float*)d_in[2];
  const float* b1  = (const float*)d_in[3];
  const float* W2  = (const float*)d_in[4];
  const float* b2  = (const float*)d_in[5];
  const float* W3  = (const float*)d_in[6];
  const float* b3  = (const float*)d_in[7];
  float* outz  = (float*)d_out;
  float* outld = outz + (size_t)512 * 128 * 128;
  short* wp = (short*)d_ws;                            // 1.38 MB packed bf16 weights
  float* c1 = (float*)((char*)d_ws + (2u << 20));      // 3.1 MB fp32 cond-bias

  hipMemsetAsync(outld, 0, 512 * sizeof(float), stream);
  prep_weights<<<336, 256, 0, stream>>>(W1, W2, W3, wp);
  prep_c1<<<6 * 512, 256, 0, stream>>>(cnd, W1, b1, c1);
  flow_kernel<<<1024, NTHR, 0, stream>>>(x, c1, b2, b3, wp, outz, outld);
}